// Round 3
// baseline (339.834 us; speedup 1.0000x reference)
//
#include <hip/hip_runtime.h>
#include <hip/hip_bf16.h>
#include <math.h>

// Problem constants
#define NN 50000
#define EE 800000
#define NEG_BIG (-3.0e38f)
#define RESCALE_THR 8.0f

// ---------------- workspace layout (bytes) ----------------
#define OFF_XLR1 ((size_t)0)                       // N*256 f32
#define SZ_XLR1  ((size_t)NN * 256 * 4)
#define OFF_H1   (OFF_XLR1 + SZ_XLR1)              // N*128 f32
#define SZ_H1    ((size_t)NN * 128 * 4)
#define OFF_XLR2 (OFF_H1 + SZ_H1)                  // N*80 f32
#define SZ_XLR2  ((size_t)NN * 80 * 4)
#define OFF_WB1  (OFF_XLR2 + SZ_XLR2)              // 128*256 f32
#define SZ_WB1   ((size_t)128 * 256 * 4)
#define OFF_BB1  (OFF_WB1 + SZ_WB1)                // 256 f32
#define SZ_BB1   ((size_t)1024)
#define OFF_WB2  (OFF_BB1 + SZ_BB1)                // 128*80 f32
#define SZ_WB2   ((size_t)128 * 80 * 4)
#define OFF_BB2  (OFF_WB2 + SZ_WB2)                // 80 f32 (pad)
#define SZ_BB2   ((size_t)512)
#define OFF_DEG  (OFF_BB2 + SZ_BB2)                // N int
#define SZ_DEG   ((size_t)NN * 4)
#define OFF_OFFS (OFF_DEG + SZ_DEG)                // (N+1) int (pad)
#define SZ_OFFS  ((size_t)((NN + 1) * 4 + 252) / 256 * 256)
#define OFF_CUR  (OFF_OFFS + SZ_OFFS)              // N int
#define SZ_CUR   ((size_t)NN * 4)
#define OFF_CSR  (OFF_CUR + SZ_CUR)                // E int
#define SZ_CSR   ((size_t)EE * 4)

// ---------------- small utility kernels ----------------
__global__ void zero_int_kernel(int* __restrict__ p, int n) {
    int i = blockIdx.x * blockDim.x + threadIdx.x;
    if (i < n) p[i] = 0;
}

__global__ void pack_weights_kernel(
    const float* __restrict__ Wl1, const float* __restrict__ bl1,
    const float* __restrict__ Wr1, const float* __restrict__ br1,
    const float* __restrict__ Wl2, const float* __restrict__ bl2,
    const float* __restrict__ Wr2, const float* __restrict__ br2,
    float* __restrict__ WB1, float* __restrict__ BB1,
    float* __restrict__ WB2, float* __restrict__ BB2) {
    int i = blockIdx.x * blockDim.x + threadIdx.x;
    if (i < 128 * 256) {
        int k = i >> 8, j = i & 255;
        WB1[i] = (j < 128) ? Wl1[k * 128 + j] : Wr1[k * 128 + j - 128];
    }
    if (i < 256) BB1[i] = (i < 128) ? bl1[i] : br1[i - 128];
    if (i < 128 * 80) {
        int k = i / 80, j = i % 80;
        WB2[i] = (j < 40) ? Wl2[k * 40 + j] : Wr2[k * 40 + j - 40];
    }
    if (i < 80) BB2[i] = (i < 40) ? bl2[i] : br2[i - 40];
}

__global__ void hist_kernel(const int* __restrict__ tgts, int* __restrict__ deg, int e_) {
    int e = blockIdx.x * blockDim.x + threadIdx.x;
    if (e < e_) atomicAdd(&deg[tgts[e]], 1);
}

// single-block inclusive scan over deg -> off[N+1], cur[i]=off[i]
__global__ __launch_bounds__(1024) void scan_kernel(
    const int* __restrict__ deg, int* __restrict__ off, int* __restrict__ cur, int n) {
    __shared__ int wsum[16];
    int carry = 0;
    int lane = threadIdx.x & 63, w = threadIdx.x >> 6;
    if (threadIdx.x == 0) off[0] = 0;
    for (int base = 0; base < n; base += 1024) {
        __syncthreads();
        int i = base + threadIdx.x;
        int v = (i < n) ? deg[i] : 0;
        int incl = v;
#pragma unroll
        for (int d = 1; d < 64; d <<= 1) {
            int t = __shfl_up(incl, d, 64);
            if (lane >= d) incl += t;
        }
        if (lane == 63) wsum[w] = incl;
        __syncthreads();
        if (threadIdx.x < 16) {
            int x = wsum[threadIdx.x];
#pragma unroll
            for (int d = 1; d < 16; d <<= 1) {
                int t = __shfl_up(x, d, 16);
                if ((int)threadIdx.x >= d) x += t;
            }
            wsum[threadIdx.x] = x;
        }
        __syncthreads();
        int add = (w > 0) ? wsum[w - 1] : 0;
        int inclTot = incl + add;
        if (i < n) {
            off[i + 1] = carry + inclTot;
            cur[i] = carry + inclTot - v;
        }
        carry += wsum[15];
    }
}

__global__ void scatter_kernel(const int* __restrict__ srcs, const int* __restrict__ tgts,
                               int* __restrict__ cur, int* __restrict__ csr, int e_) {
    int e = blockIdx.x * blockDim.x + threadIdx.x;
    if (e < e_) {
        int t = tgts[e];
        int pos = atomicAdd(&cur[t], 1);
        csr[pos] = srcs[e];
    }
}

// ---------------- f32 GEMM: C[M,N] = A[M,K] @ B[K,N] + bias[N] ----------------
// BM=128 BN=64 BK=16, 256 threads, 8x4 micro-tile (compute-bound config).
// Requires K % 16 == 0.
__global__ __launch_bounds__(256) void gemm_bias_kernel(
    const float* __restrict__ A, const float* __restrict__ B,
    const float* __restrict__ bias, float* __restrict__ C,
    int M, int N, int K) {
    __shared__ float As[16][132];  // [k][row], padded
    __shared__ float Bs[16][68];   // [k][col], padded
    int tid = threadIdx.x;
    int r0 = blockIdx.y * 128;
    int n0 = blockIdx.x * 64;
    int trow = tid >> 4;          // 0..15 -> rows trow*8..+7
    int tcol = tid & 15;          // 0..15 -> cols tcol*4..+3
    // A staging: thread loads 8 floats of one row
    int arow = tid >> 1;          // 0..127
    int akq = (tid & 1) << 3;     // 0 or 8
    // B staging: thread loads 4 floats of one row
    int bk = tid >> 4;            // 0..15
    int bnq = (tid & 15) << 2;    // 0..60
    float acc[8][4] = {};
    for (int k0 = 0; k0 < K; k0 += 16) {
        float4 a0 = make_float4(0.f, 0.f, 0.f, 0.f);
        float4 a1 = make_float4(0.f, 0.f, 0.f, 0.f);
        if (r0 + arow < M) {
            const float* ap = &A[(size_t)(r0 + arow) * K + k0 + akq];
            a0 = *(const float4*)ap;
            a1 = *(const float4*)(ap + 4);
        }
        As[akq + 0][arow] = a0.x;
        As[akq + 1][arow] = a0.y;
        As[akq + 2][arow] = a0.z;
        As[akq + 3][arow] = a0.w;
        As[akq + 4][arow] = a1.x;
        As[akq + 5][arow] = a1.y;
        As[akq + 6][arow] = a1.z;
        As[akq + 7][arow] = a1.w;
        float4 bv;
        int bn = n0 + bnq;
        if (bn + 3 < N) {
            bv = *(const float4*)&B[(size_t)(k0 + bk) * N + bn];
        } else {
            float t0 = (bn + 0 < N) ? B[(size_t)(k0 + bk) * N + bn + 0] : 0.f;
            float t1 = (bn + 1 < N) ? B[(size_t)(k0 + bk) * N + bn + 1] : 0.f;
            float t2 = (bn + 2 < N) ? B[(size_t)(k0 + bk) * N + bn + 2] : 0.f;
            float t3 = (bn + 3 < N) ? B[(size_t)(k0 + bk) * N + bn + 3] : 0.f;
            bv = make_float4(t0, t1, t2, t3);
        }
        *(float4*)&Bs[bk][bnq] = bv;
        __syncthreads();
#pragma unroll
        for (int k = 0; k < 16; ++k) {
            float4 av0 = *(const float4*)&As[k][trow << 3];
            float4 av1 = *(const float4*)&As[k][(trow << 3) + 4];
            float4 b = *(const float4*)&Bs[k][tcol << 2];
            float ar[8] = {av0.x, av0.y, av0.z, av0.w, av1.x, av1.y, av1.z, av1.w};
            float br[4] = {b.x, b.y, b.z, b.w};
#pragma unroll
            for (int i = 0; i < 8; ++i)
#pragma unroll
                for (int j = 0; j < 4; ++j) acc[i][j] = fmaf(ar[i], br[j], acc[i][j]);
        }
        __syncthreads();
    }
#pragma unroll
    for (int i = 0; i < 8; ++i) {
        int r = r0 + (trow << 3) + i;
        if (r >= M) break;
#pragma unroll
        for (int j = 0; j < 4; ++j) {
            int c = n0 + (tcol << 2) + j;
            if (c < N) C[(size_t)r * N + c] = acc[i][j] + bias[c];
        }
    }
}

__device__ __forceinline__ float lrelu02(float h) { return fmaxf(h, 0.2f * h); }

// ---------------- layer-1 fused edge kernel (4 edges x 16 lanes per wave) ----
// Lane (grp=lane>>4, sub=lane&15) holds channels [sub*8, sub*8+8) of edge grp.
// Online softmax with defer-max: m is a per-lane REFERENCE (not strict max);
// rescale only when any lane sees t - m > RESCALE_THR. p bounded by e^8.
__global__ __launch_bounds__(256) void gat_edge1_kernel(
    const float* __restrict__ XLR, const int* __restrict__ off, const int* __restrict__ csr,
    const float* __restrict__ att, const float* __restrict__ b1,
    const float* __restrict__ g1, const float* __restrict__ be1,
    float* __restrict__ H1) {
    int wid = threadIdx.x >> 6;
    int lane = threadIdx.x & 63;
    int node = blockIdx.x * 4 + wid;
    if (node >= NN) return;
    int grp = lane >> 4;
    int sub = lane & 15;
    int cbase = sub << 3;
    const float* xrrow = &XLR[(size_t)node * 256 + 128];
    float4 xrA = *(const float4*)&xrrow[cbase];
    float4 xrB = *(const float4*)&xrrow[cbase + 4];
    float4 atA = *(const float4*)&att[cbase];
    float4 atB = *(const float4*)&att[cbase + 4];
    float m = NEG_BIG, s = 0.f;
    float acc[8] = {};
    int jb = off[node], je = off[node + 1];
    int nb = (je - jb + 3) >> 2;
    for (int k = 0; k < nb; ++k) {
        int eidx = jb + (k << 2) + grp;
        bool valid = eidx < je;
        int src = valid ? csr[eidx] : 0;
        const float* xlrow = &XLR[(size_t)src * 256];
        float4 xlA = *(const float4*)&xlrow[cbase];
        float4 xlB = *(const float4*)&xlrow[cbase + 4];
        float t = lrelu02(xlA.x + xrA.x) * atA.x;
        t = fmaf(lrelu02(xlA.y + xrA.y), atA.y, t);
        t = fmaf(lrelu02(xlA.z + xrA.z), atA.z, t);
        t = fmaf(lrelu02(xlA.w + xrA.w), atA.w, t);
        t = fmaf(lrelu02(xlB.x + xrB.x), atB.x, t);
        t = fmaf(lrelu02(xlB.y + xrB.y), atB.y, t);
        t = fmaf(lrelu02(xlB.z + xrB.z), atB.z, t);
        t = fmaf(lrelu02(xlB.w + xrB.w), atB.w, t);
        t += __shfl_xor(t, 1, 64);
        t += __shfl_xor(t, 2, 64);
        bool need = valid && (t - m > RESCALE_THR);
        if (__any(need)) {  // rare: ~once per node
            float nm = need ? t : m;
            float sc = __expf(m - nm);
#pragma unroll
            for (int j = 0; j < 8; ++j) acc[j] *= sc;
            s *= sc;
            m = nm;
        }
        float p = valid ? __expf(t - m) : 0.f;
        acc[0] = fmaf(p, xlA.x, acc[0]);
        acc[1] = fmaf(p, xlA.y, acc[1]);
        acc[2] = fmaf(p, xlA.z, acc[2]);
        acc[3] = fmaf(p, xlA.w, acc[3]);
        acc[4] = fmaf(p, xlB.x, acc[4]);
        acc[5] = fmaf(p, xlB.y, acc[5]);
        acc[6] = fmaf(p, xlB.z, acc[6]);
        acc[7] = fmaf(p, xlB.w, acc[7]);
        s += p;
    }
    // merge the 4 groups' states (reference-agnostic online-softmax merge)
#pragma unroll
    for (int d = 16; d <= 32; d <<= 1) {
        float mo = __shfl_xor(m, d, 64);
        float so = __shfl_xor(s, d, 64);
        float ao[8];
#pragma unroll
        for (int j = 0; j < 8; ++j) ao[j] = __shfl_xor(acc[j], d, 64);
        float nm = fmaxf(m, mo);
        float sa = __expf(m - nm), sb = __expf(mo - nm);
#pragma unroll
        for (int j = 0; j < 8; ++j) acc[j] = acc[j] * sa + ao[j] * sb;
        s = s * sa + so * sb;
        m = nm;
    }
    float inv = 1.f / (s + 1e-16f);
    float4 bA = *(const float4*)&b1[cbase];
    float4 bB = *(const float4*)&b1[cbase + 4];
    float o[8];
    o[0] = acc[0] * inv + bA.x;
    o[1] = acc[1] * inv + bA.y;
    o[2] = acc[2] * inv + bA.z;
    o[3] = acc[3] * inv + bA.w;
    o[4] = acc[4] * inv + bB.x;
    o[5] = acc[5] * inv + bB.y;
    o[6] = acc[6] * inv + bB.z;
    o[7] = acc[7] * inv + bB.w;
    float sum = 0.f, sq = 0.f;
#pragma unroll
    for (int j = 0; j < 8; ++j) {
        sum += o[j];
        sq = fmaf(o[j], o[j], sq);
    }
#pragma unroll
    for (int d = 1; d <= 8; d <<= 1) {
        sum += __shfl_xor(sum, d, 64);
        sq += __shfl_xor(sq, d, 64);
    }
    float mu = sum * (1.f / 128.f);
    float var = sq * (1.f / 128.f) - mu * mu;
    float rs = rsqrtf(var + 1e-5f);
    if (grp == 0) {
        float4 gA = *(const float4*)&g1[cbase];
        float4 gB = *(const float4*)&g1[cbase + 4];
        float4 eA = *(const float4*)&be1[cbase];
        float4 eB = *(const float4*)&be1[cbase + 4];
        float y[8];
        y[0] = (o[0] - mu) * rs * gA.x + eA.x;
        y[1] = (o[1] - mu) * rs * gA.y + eA.y;
        y[2] = (o[2] - mu) * rs * gA.z + eA.z;
        y[3] = (o[3] - mu) * rs * gA.w + eA.w;
        y[4] = (o[4] - mu) * rs * gB.x + eB.x;
        y[5] = (o[5] - mu) * rs * gB.y + eB.y;
        y[6] = (o[6] - mu) * rs * gB.z + eB.z;
        y[7] = (o[7] - mu) * rs * gB.w + eB.w;
#pragma unroll
        for (int j = 0; j < 8; ++j) y[j] = y[j] > 0.f ? y[j] : expm1f(y[j]);
        float* hrow = &H1[(size_t)node * 128 + cbase];
        *(float4*)&hrow[0] = make_float4(y[0], y[1], y[2], y[3]);
        *(float4*)&hrow[4] = make_float4(y[4], y[5], y[6], y[7]);
    }
}

// ---------------- layer-2 fused edge kernel (4 edges x 16 lanes) -------------
__global__ __launch_bounds__(256) void gat_edge2_kernel(
    const float* __restrict__ XLR2, const int* __restrict__ off, const int* __restrict__ csr,
    const float* __restrict__ att2, const float* __restrict__ b2,
    float* __restrict__ Y) {
    int wid = threadIdx.x >> 6;
    int lane = threadIdx.x & 63;
    int node = blockIdx.x * 4 + wid;
    if (node >= NN) return;
    int grp = lane >> 4;
    int sub = lane & 15;
    bool chact = sub < 10;
    int cbase = sub << 2;
    const size_t nb_ = (size_t)node * 80;
    float4 xr = make_float4(0.f, 0.f, 0.f, 0.f);
    float4 at = make_float4(0.f, 0.f, 0.f, 0.f);
    if (chact) {
        xr = *(const float4*)&XLR2[nb_ + 40 + cbase];
        at = *(const float4*)&att2[cbase];
    }
    float m = NEG_BIG, s = 0.f;
    float acc[4] = {};
    int jb = off[node], je = off[node + 1];
    int nb = (je - jb + 3) >> 2;
    for (int k = 0; k < nb; ++k) {
        int eidx = jb + (k << 2) + grp;
        bool valid = eidx < je;
        int src = valid ? csr[eidx] : 0;
        float4 xl = make_float4(0.f, 0.f, 0.f, 0.f);
        if (chact) xl = *(const float4*)&XLR2[(size_t)src * 80 + cbase];
        float t = lrelu02(xl.x + xr.x) * at.x;
        t = fmaf(lrelu02(xl.y + xr.y), at.y, t);
        t = fmaf(lrelu02(xl.z + xr.z), at.z, t);
        t = fmaf(lrelu02(xl.w + xr.w), at.w, t);
        t += __shfl_xor(t, 1, 64);
        t += __shfl_xor(t, 2, 64);
        t += __shfl_xor(t, 4, 64);
        t += __shfl_xor(t, 8, 64);
        bool need = valid && (t - m > RESCALE_THR);
        if (__any(need)) {
            float nm = need ? t : m;
            float sc = __expf(m - nm);
            acc[0] *= sc;
            acc[1] *= sc;
            acc[2] *= sc;
            acc[3] *= sc;
            s *= sc;
            m = nm;
        }
        float p = valid ? __expf(t - m) : 0.f;
        acc[0] = fmaf(p, xl.x, acc[0]);
        acc[1] = fmaf(p, xl.y, acc[1]);
        acc[2] = fmaf(p, xl.z, acc[2]);
        acc[3] = fmaf(p, xl.w, acc[3]);
        s += p;
    }
#pragma unroll
    for (int d = 16; d <= 32; d <<= 1) {
        float mo = __shfl_xor(m, d, 64);
        float so = __shfl_xor(s, d, 64);
        float a0 = __shfl_xor(acc[0], d, 64);
        float a1 = __shfl_xor(acc[1], d, 64);
        float a2 = __shfl_xor(acc[2], d, 64);
        float a3 = __shfl_xor(acc[3], d, 64);
        float nm = fmaxf(m, mo);
        float sa = __expf(m - nm), sb = __expf(mo - nm);
        acc[0] = acc[0] * sa + a0 * sb;
        acc[1] = acc[1] * sa + a1 * sb;
        acc[2] = acc[2] * sa + a2 * sb;
        acc[3] = acc[3] * sa + a3 * sb;
        s = s * sa + so * sb;
        m = nm;
    }
    if (grp == 0 && chact) {
        float inv = 1.f / (s + 1e-16f);
        float4 bb = *(const float4*)&b2[cbase];
        float4 y;
        y.x = acc[0] * inv + bb.x;
        y.y = acc[1] * inv + bb.y;
        y.z = acc[2] * inv + bb.z;
        y.w = acc[3] * inv + bb.w;
        *(float4*)&Y[(size_t)node * 40 + cbase] = y;
    }
}

// ---------------- launch ----------------
extern "C" void kernel_launch(void* const* d_in, const int* in_sizes, int n_in,
                              void* d_out, int out_size, void* d_ws, size_t ws_size,
                              hipStream_t stream) {
    const float* x = (const float*)d_in[0];
    const int* ei = (const int*)d_in[1];
    const float* Wl1 = (const float*)d_in[2];
    const float* bl1 = (const float*)d_in[3];
    const float* Wr1 = (const float*)d_in[4];
    const float* br1 = (const float*)d_in[5];
    const float* att1 = (const float*)d_in[6];
    const float* b1 = (const float*)d_in[7];
    const float* g1 = (const float*)d_in[8];
    const float* be1 = (const float*)d_in[9];
    const float* Wl2 = (const float*)d_in[10];
    const float* bl2 = (const float*)d_in[11];
    const float* Wr2 = (const float*)d_in[12];
    const float* br2 = (const float*)d_in[13];
    const float* att2 = (const float*)d_in[14];
    const float* b2 = (const float*)d_in[15];

    const int* srcs = ei;
    const int* tgts = ei + EE;

    char* ws = (char*)d_ws;
    float* XLR1 = (float*)(ws + OFF_XLR1);
    float* H1 = (float*)(ws + OFF_H1);
    float* XLR2 = (float*)(ws + OFF_XLR2);
    float* WB1 = (float*)(ws + OFF_WB1);
    float* BB1 = (float*)(ws + OFF_BB1);
    float* WB2 = (float*)(ws + OFF_WB2);
    float* BB2 = (float*)(ws + OFF_BB2);
    int* DEG = (int*)(ws + OFF_DEG);
    int* OFFS = (int*)(ws + OFF_OFFS);
    int* CUR = (int*)(ws + OFF_CUR);
    int* CSR = (int*)(ws + OFF_CSR);

    float* Y = (float*)d_out;

    pack_weights_kernel<<<(128 * 256 + 255) / 256, 256, 0, stream>>>(
        Wl1, bl1, Wr1, br1, Wl2, bl2, Wr2, br2, WB1, BB1, WB2, BB2);

    zero_int_kernel<<<(NN + 255) / 256, 256, 0, stream>>>(DEG, NN);
    hist_kernel<<<(EE + 255) / 256, 256, 0, stream>>>(tgts, DEG, EE);
    scan_kernel<<<1, 1024, 0, stream>>>(DEG, OFFS, CUR, NN);
    scatter_kernel<<<(EE + 255) / 256, 256, 0, stream>>>(srcs, tgts, CUR, CSR, EE);

    {
        dim3 grid(256 / 64, (NN + 127) / 128);
        gemm_bias_kernel<<<grid, 256, 0, stream>>>(x, WB1, BB1, XLR1, NN, 256, 128);
    }

    gat_edge1_kernel<<<(NN + 3) / 4, 256, 0, stream>>>(XLR1, OFFS, CSR, att1, b1, g1, be1, H1);

    {
        dim3 grid((80 + 63) / 64, (NN + 127) / 128);
        gemm_bias_kernel<<<grid, 256, 0, stream>>>(H1, WB2, BB2, XLR2, NN, 80, 128);
    }

    gat_edge2_kernel<<<(NN + 3) / 4, 256, 0, stream>>>(XLR2, OFFS, CSR, att2, b2, Y);
}

// Round 4
// 284.441 us; speedup vs baseline: 1.1947x; 1.1947x over previous
//
#include <hip/hip_runtime.h>
#include <hip/hip_bf16.h>
#include <math.h>

// Problem constants
#define NN 50000
#define EE 800000
#define NEG_BIG (-3.0e38f)
#define RESCALE_THR 8.0f

typedef __attribute__((ext_vector_type(8))) short bf16x8;
typedef __attribute__((ext_vector_type(4))) float f32x4;
typedef __attribute__((ext_vector_type(8))) unsigned short ushortx8;

// ---------------- workspace layout (bytes) ----------------
#define OFF_XLR1 ((size_t)0)                        // N*256 f32
#define SZ_XLR1  ((size_t)NN * 256 * 4)             // 51,200,000
#define OFF_H1B  (OFF_XLR1 + SZ_XLR1)               // N*128 bf16
#define SZ_H1B   ((size_t)NN * 128 * 2)             // 12,800,000
#define OFF_XLR2 (OFF_H1B + SZ_H1B)                 // N*80 f32
#define SZ_XLR2  ((size_t)NN * 80 * 4)              // 16,000,000
#define OFF_XBF  (OFF_XLR2 + SZ_XLR2)               // N*128 bf16
#define SZ_XBF   ((size_t)NN * 128 * 2)             // 12,800,000
#define OFF_BP1  (OFF_XBF + SZ_XBF)                 // 4*16*64*8 bf16
#define SZ_BP1   ((size_t)32768 * 2)
#define OFF_BP2  (OFF_BP1 + SZ_BP1)                 // 4*5*64*8 bf16
#define SZ_BP2   ((size_t)10240 * 2)
#define OFF_BB1  (OFF_BP2 + SZ_BP2)                 // 256 f32
#define SZ_BB1   ((size_t)1024)
#define OFF_BB2  (OFF_BB1 + SZ_BB1)                 // 80 f32 (pad)
#define SZ_BB2   ((size_t)512)
#define OFF_DEG  (OFF_BB2 + SZ_BB2)                 // N int
#define SZ_DEG   ((size_t)NN * 4)
#define OFF_OFFS (OFF_DEG + SZ_DEG)                 // (N+1) int
#define SZ_OFFS  ((size_t)(NN + 1) * 4)
#define OFF_CUR  (OFF_OFFS + SZ_OFFS)               // N int
#define SZ_CUR   ((size_t)NN * 4)
#define OFF_CSR  (OFF_CUR + SZ_CUR)                 // E int
#define SZ_CSR   ((size_t)EE * 4)

__device__ __forceinline__ unsigned short f2bf(float f) {
    union { float f; unsigned u; } v;
    v.f = f;
    unsigned r = v.u + 0x7fffu + ((v.u >> 16) & 1u);
    return (unsigned short)(r >> 16);
}

// ---------------- small utility kernels ----------------
__global__ void zero_int_kernel(int* __restrict__ p, int n) {
    int i = blockIdx.x * blockDim.x + threadIdx.x;
    if (i < n) p[i] = 0;
}

// pack weights into bf16 MFMA B-fragment layout:
// BP[((kt*NT + nt)*64 + lane)*8 + j] = W[k = kt*32 + (lane>>4)*8 + j][n = nt*16 + (lane&15)]
__global__ void pack_weights_kernel(
    const float* __restrict__ Wl1, const float* __restrict__ bl1,
    const float* __restrict__ Wr1, const float* __restrict__ br1,
    const float* __restrict__ Wl2, const float* __restrict__ bl2,
    const float* __restrict__ Wr2, const float* __restrict__ br2,
    unsigned short* __restrict__ BP1, float* __restrict__ BB1,
    unsigned short* __restrict__ BP2, float* __restrict__ BB2) {
    int i = blockIdx.x * blockDim.x + threadIdx.x;
    if (i < 32768) {  // layer 1: NT=16
        int j = i & 7, l = (i >> 3) & 63, nt = (i >> 9) & 15, kt = i >> 13;
        int k = kt * 32 + ((l >> 4) << 3) + j;
        int n = nt * 16 + (l & 15);
        float v = (n < 128) ? Wl1[k * 128 + n] : Wr1[k * 128 + (n - 128)];
        BP1[i] = f2bf(v);
    }
    if (i < 10240) {  // layer 2: NT=5
        int j = i & 7, l = (i >> 3) & 63;
        int rest = i >> 9;  // 0..19
        int nt = rest % 5, kt = rest / 5;
        int k = kt * 32 + ((l >> 4) << 3) + j;
        int n = nt * 16 + (l & 15);
        float v = (n < 40) ? Wl2[k * 40 + n] : Wr2[k * 40 + (n - 40)];
        BP2[i] = f2bf(v);
    }
    if (i < 256) BB1[i] = (i < 128) ? bl1[i] : br1[i - 128];
    if (i < 80) BB2[i] = (i < 40) ? bl2[i] : br2[i - 40];
}

// f32 -> bf16, 8 elements per thread
__global__ void cvt_bf16_kernel(const float* __restrict__ in, unsigned short* __restrict__ out,
                                int n8) {
    int i = blockIdx.x * blockDim.x + threadIdx.x;
    if (i >= n8) return;
    const float4* p = (const float4*)in + (size_t)i * 2;
    float4 v0 = p[0], v1 = p[1];
    ushortx8 o;
    o[0] = f2bf(v0.x); o[1] = f2bf(v0.y); o[2] = f2bf(v0.z); o[3] = f2bf(v0.w);
    o[4] = f2bf(v1.x); o[5] = f2bf(v1.y); o[6] = f2bf(v1.z); o[7] = f2bf(v1.w);
    *((ushortx8*)out + i) = o;
}

__global__ void hist_kernel(const int* __restrict__ tgts, int* __restrict__ deg, int e_) {
    int e = blockIdx.x * blockDim.x + threadIdx.x;
    if (e < e_) atomicAdd(&deg[tgts[e]], 1);
}

// single-block inclusive scan over deg -> off[N+1], cur[i]=off[i]
__global__ __launch_bounds__(1024) void scan_kernel(
    const int* __restrict__ deg, int* __restrict__ off, int* __restrict__ cur, int n) {
    __shared__ int wsum[16];
    int carry = 0;
    int lane = threadIdx.x & 63, w = threadIdx.x >> 6;
    if (threadIdx.x == 0) off[0] = 0;
    for (int base = 0; base < n; base += 1024) {
        __syncthreads();
        int i = base + threadIdx.x;
        int v = (i < n) ? deg[i] : 0;
        int incl = v;
#pragma unroll
        for (int d = 1; d < 64; d <<= 1) {
            int t = __shfl_up(incl, d, 64);
            if (lane >= d) incl += t;
        }
        if (lane == 63) wsum[w] = incl;
        __syncthreads();
        if (threadIdx.x < 16) {
            int x = wsum[threadIdx.x];
#pragma unroll
            for (int d = 1; d < 16; d <<= 1) {
                int t = __shfl_up(x, d, 16);
                if ((int)threadIdx.x >= d) x += t;
            }
            wsum[threadIdx.x] = x;
        }
        __syncthreads();
        int add = (w > 0) ? wsum[w - 1] : 0;
        int inclTot = incl + add;
        if (i < n) {
            off[i + 1] = carry + inclTot;
            cur[i] = carry + inclTot - v;
        }
        carry += wsum[15];
    }
}

__global__ void scatter_kernel(const int* __restrict__ srcs, const int* __restrict__ tgts,
                               int* __restrict__ cur, int* __restrict__ csr, int e_) {
    int e = blockIdx.x * blockDim.x + threadIdx.x;
    if (e < e_) {
        int t = tgts[e];
        int pos = atomicAdd(&cur[t], 1);
        csr[pos] = srcs[e];
    }
}

// ---------------- bf16 MFMA GEMM: C[M,N] = A[M,128] @ B[128,N] + bias ----------
// One wave per 16 rows. M must be a multiple of 16 (50000 = 3125*16).
// A frag: lane l, reg j -> row = l&15, k = (l>>4)*8 + j  (16B contiguous load)
// B frag: from packed BP layout (coalesced 16B/lane)
// D: col = l&15, row = (l>>4)*4 + j   [verified m89]
__global__ __launch_bounds__(256) void gemm_mfma_kernel(
    const unsigned short* __restrict__ Abf, const unsigned short* __restrict__ BP,
    const float* __restrict__ bias, float* __restrict__ C, int M, int NT) {
    int wave = (blockIdx.x * blockDim.x + threadIdx.x) >> 6;
    int lane = threadIdx.x & 63;
    int r0 = wave * 16;
    if (r0 >= M) return;
    int koff = (lane >> 4) << 3;
    const unsigned short* ap = &Abf[(size_t)(r0 + (lane & 15)) * 128 + koff];
    bf16x8 a0 = *(const bf16x8*)(ap);
    bf16x8 a1 = *(const bf16x8*)(ap + 32);
    bf16x8 a2 = *(const bf16x8*)(ap + 64);
    bf16x8 a3 = *(const bf16x8*)(ap + 96);
    int N = NT << 4;
    int col = lane & 15;
    int rb = r0 + ((lane >> 4) << 2);
    size_t ktStride = (size_t)NT * 512;  // NT*64*8
    for (int nt = 0; nt < NT; ++nt) {
        const unsigned short* bp = &BP[((size_t)nt * 64 + lane) * 8];
        f32x4 acc = {0.f, 0.f, 0.f, 0.f};
        acc = __builtin_amdgcn_mfma_f32_16x16x32_bf16(a0, *(const bf16x8*)(bp), acc, 0, 0, 0);
        acc = __builtin_amdgcn_mfma_f32_16x16x32_bf16(a1, *(const bf16x8*)(bp + ktStride), acc, 0, 0, 0);
        acc = __builtin_amdgcn_mfma_f32_16x16x32_bf16(a2, *(const bf16x8*)(bp + 2 * ktStride), acc, 0, 0, 0);
        acc = __builtin_amdgcn_mfma_f32_16x16x32_bf16(a3, *(const bf16x8*)(bp + 3 * ktStride), acc, 0, 0, 0);
        int c = (nt << 4) + col;
        float bb = bias[c];
#pragma unroll
        for (int j = 0; j < 4; ++j) C[(size_t)(rb + j) * N + c] = acc[j] + bb;
    }
}

__device__ __forceinline__ float lrelu02(float h) { return fmaxf(h, 0.2f * h); }

// ---------------- layer-1 fused edge kernel (4 edges x 16 lanes per wave) ----
// Writes H1 as bf16 (feeds the layer-2 MFMA GEMM directly).
__global__ __launch_bounds__(256) void gat_edge1_kernel(
    const float* __restrict__ XLR, const int* __restrict__ off, const int* __restrict__ csr,
    const float* __restrict__ att, const float* __restrict__ b1,
    const float* __restrict__ g1, const float* __restrict__ be1,
    unsigned short* __restrict__ H1B) {
    int wid = threadIdx.x >> 6;
    int lane = threadIdx.x & 63;
    int node = blockIdx.x * 4 + wid;
    if (node >= NN) return;
    int grp = lane >> 4;
    int sub = lane & 15;
    int cbase = sub << 3;
    const float* xrrow = &XLR[(size_t)node * 256 + 128];
    float4 xrA = *(const float4*)&xrrow[cbase];
    float4 xrB = *(const float4*)&xrrow[cbase + 4];
    float4 atA = *(const float4*)&att[cbase];
    float4 atB = *(const float4*)&att[cbase + 4];
    float m = NEG_BIG, s = 0.f;
    float acc[8] = {};
    int jb = off[node], je = off[node + 1];
    int nb = (je - jb + 3) >> 2;
#pragma unroll 2
    for (int k = 0; k < nb; ++k) {
        int eidx = jb + (k << 2) + grp;
        bool valid = eidx < je;
        int src = valid ? csr[eidx] : 0;
        const float* xlrow = &XLR[(size_t)src * 256];
        float4 xlA = *(const float4*)&xlrow[cbase];
        float4 xlB = *(const float4*)&xlrow[cbase + 4];
        float t = lrelu02(xlA.x + xrA.x) * atA.x;
        t = fmaf(lrelu02(xlA.y + xrA.y), atA.y, t);
        t = fmaf(lrelu02(xlA.z + xrA.z), atA.z, t);
        t = fmaf(lrelu02(xlA.w + xrA.w), atA.w, t);
        t = fmaf(lrelu02(xlB.x + xrB.x), atB.x, t);
        t = fmaf(lrelu02(xlB.y + xrB.y), atB.y, t);
        t = fmaf(lrelu02(xlB.z + xrB.z), atB.z, t);
        t = fmaf(lrelu02(xlB.w + xrB.w), atB.w, t);
        t += __shfl_xor(t, 1, 64);
        t += __shfl_xor(t, 2, 64);
        bool need = valid && (t - m > RESCALE_THR);
        if (__any(need)) {  // rare: ~once per node
            float nm = need ? t : m;
            float sc = __expf(m - nm);
#pragma unroll
            for (int j = 0; j < 8; ++j) acc[j] *= sc;
            s *= sc;
            m = nm;
        }
        float p = valid ? __expf(t - m) : 0.f;
        acc[0] = fmaf(p, xlA.x, acc[0]);
        acc[1] = fmaf(p, xlA.y, acc[1]);
        acc[2] = fmaf(p, xlA.z, acc[2]);
        acc[3] = fmaf(p, xlA.w, acc[3]);
        acc[4] = fmaf(p, xlB.x, acc[4]);
        acc[5] = fmaf(p, xlB.y, acc[5]);
        acc[6] = fmaf(p, xlB.z, acc[6]);
        acc[7] = fmaf(p, xlB.w, acc[7]);
        s += p;
    }
    // merge the 4 groups' states (reference-agnostic online-softmax merge)
#pragma unroll
    for (int d = 16; d <= 32; d <<= 1) {
        float mo = __shfl_xor(m, d, 64);
        float so = __shfl_xor(s, d, 64);
        float ao[8];
#pragma unroll
        for (int j = 0; j < 8; ++j) ao[j] = __shfl_xor(acc[j], d, 64);
        float nm = fmaxf(m, mo);
        float sa = __expf(m - nm), sb = __expf(mo - nm);
#pragma unroll
        for (int j = 0; j < 8; ++j) acc[j] = acc[j] * sa + ao[j] * sb;
        s = s * sa + so * sb;
        m = nm;
    }
    float inv = 1.f / (s + 1e-16f);
    float4 bA = *(const float4*)&b1[cbase];
    float4 bB = *(const float4*)&b1[cbase + 4];
    float o[8];
    o[0] = acc[0] * inv + bA.x;
    o[1] = acc[1] * inv + bA.y;
    o[2] = acc[2] * inv + bA.z;
    o[3] = acc[3] * inv + bA.w;
    o[4] = acc[4] * inv + bB.x;
    o[5] = acc[5] * inv + bB.y;
    o[6] = acc[6] * inv + bB.z;
    o[7] = acc[7] * inv + bB.w;
    float sum = 0.f, sq = 0.f;
#pragma unroll
    for (int j = 0; j < 8; ++j) {
        sum += o[j];
        sq = fmaf(o[j], o[j], sq);
    }
#pragma unroll
    for (int d = 1; d <= 8; d <<= 1) {
        sum += __shfl_xor(sum, d, 64);
        sq += __shfl_xor(sq, d, 64);
    }
    float mu = sum * (1.f / 128.f);
    float var = sq * (1.f / 128.f) - mu * mu;
    float rs = rsqrtf(var + 1e-5f);
    if (grp == 0) {
        float4 gA = *(const float4*)&g1[cbase];
        float4 gB = *(const float4*)&g1[cbase + 4];
        float4 eA = *(const float4*)&be1[cbase];
        float4 eB = *(const float4*)&be1[cbase + 4];
        float y[8];
        y[0] = (o[0] - mu) * rs * gA.x + eA.x;
        y[1] = (o[1] - mu) * rs * gA.y + eA.y;
        y[2] = (o[2] - mu) * rs * gA.z + eA.z;
        y[3] = (o[3] - mu) * rs * gA.w + eA.w;
        y[4] = (o[4] - mu) * rs * gB.x + eB.x;
        y[5] = (o[5] - mu) * rs * gB.y + eB.y;
        y[6] = (o[6] - mu) * rs * gB.z + eB.z;
        y[7] = (o[7] - mu) * rs * gB.w + eB.w;
        ushortx8 hw;
#pragma unroll
        for (int j = 0; j < 8; ++j) {
            float yy = y[j] > 0.f ? y[j] : expm1f(y[j]);
            hw[j] = f2bf(yy);
        }
        *(ushortx8*)&H1B[(size_t)node * 128 + cbase] = hw;
    }
}

// ---------------- layer-2 fused edge kernel (4 edges x 16 lanes) -------------
__global__ __launch_bounds__(256) void gat_edge2_kernel(
    const float* __restrict__ XLR2, const int* __restrict__ off, const int* __restrict__ csr,
    const float* __restrict__ att2, const float* __restrict__ b2,
    float* __restrict__ Y) {
    int wid = threadIdx.x >> 6;
    int lane = threadIdx.x & 63;
    int node = blockIdx.x * 4 + wid;
    if (node >= NN) return;
    int grp = lane >> 4;
    int sub = lane & 15;
    bool chact = sub < 10;
    int cbase = sub << 2;
    const size_t nb_ = (size_t)node * 80;
    float4 xr = make_float4(0.f, 0.f, 0.f, 0.f);
    float4 at = make_float4(0.f, 0.f, 0.f, 0.f);
    if (chact) {
        xr = *(const float4*)&XLR2[nb_ + 40 + cbase];
        at = *(const float4*)&att2[cbase];
    }
    float m = NEG_BIG, s = 0.f;
    float acc[4] = {};
    int jb = off[node], je = off[node + 1];
    int nb = (je - jb + 3) >> 2;
#pragma unroll 2
    for (int k = 0; k < nb; ++k) {
        int eidx = jb + (k << 2) + grp;
        bool valid = eidx < je;
        int src = valid ? csr[eidx] : 0;
        float4 xl = make_float4(0.f, 0.f, 0.f, 0.f);
        if (chact) xl = *(const float4*)&XLR2[(size_t)src * 80 + cbase];
        float t = lrelu02(xl.x + xr.x) * at.x;
        t = fmaf(lrelu02(xl.y + xr.y), at.y, t);
        t = fmaf(lrelu02(xl.z + xr.z), at.z, t);
        t = fmaf(lrelu02(xl.w + xr.w), at.w, t);
        t += __shfl_xor(t, 1, 64);
        t += __shfl_xor(t, 2, 64);
        t += __shfl_xor(t, 4, 64);
        t += __shfl_xor(t, 8, 64);
        bool need = valid && (t - m > RESCALE_THR);
        if (__any(need)) {
            float nm = need ? t : m;
            float sc = __expf(m - nm);
            acc[0] *= sc;
            acc[1] *= sc;
            acc[2] *= sc;
            acc[3] *= sc;
            s *= sc;
            m = nm;
        }
        float p = valid ? __expf(t - m) : 0.f;
        acc[0] = fmaf(p, xl.x, acc[0]);
        acc[1] = fmaf(p, xl.y, acc[1]);
        acc[2] = fmaf(p, xl.z, acc[2]);
        acc[3] = fmaf(p, xl.w, acc[3]);
        s += p;
    }
#pragma unroll
    for (int d = 16; d <= 32; d <<= 1) {
        float mo = __shfl_xor(m, d, 64);
        float so = __shfl_xor(s, d, 64);
        float a0 = __shfl_xor(acc[0], d, 64);
        float a1 = __shfl_xor(acc[1], d, 64);
        float a2 = __shfl_xor(acc[2], d, 64);
        float a3 = __shfl_xor(acc[3], d, 64);
        float nm = fmaxf(m, mo);
        float sa = __expf(m - nm), sb = __expf(mo - nm);
        acc[0] = acc[0] * sa + a0 * sb;
        acc[1] = acc[1] * sa + a1 * sb;
        acc[2] = acc[2] * sa + a2 * sb;
        acc[3] = acc[3] * sa + a3 * sb;
        s = s * sa + so * sb;
        m = nm;
    }
    if (grp == 0 && chact) {
        float inv = 1.f / (s + 1e-16f);
        float4 bb = *(const float4*)&b2[cbase];
        float4 y;
        y.x = acc[0] * inv + bb.x;
        y.y = acc[1] * inv + bb.y;
        y.z = acc[2] * inv + bb.z;
        y.w = acc[3] * inv + bb.w;
        *(float4*)&Y[(size_t)node * 40 + cbase] = y;
    }
}

// ---------------- launch ----------------
extern "C" void kernel_launch(void* const* d_in, const int* in_sizes, int n_in,
                              void* d_out, int out_size, void* d_ws, size_t ws_size,
                              hipStream_t stream) {
    const float* x = (const float*)d_in[0];
    const int* ei = (const int*)d_in[1];
    const float* Wl1 = (const float*)d_in[2];
    const float* bl1 = (const float*)d_in[3];
    const float* Wr1 = (const float*)d_in[4];
    const float* br1 = (const float*)d_in[5];
    const float* att1 = (const float*)d_in[6];
    const float* b1 = (const float*)d_in[7];
    const float* g1 = (const float*)d_in[8];
    const float* be1 = (const float*)d_in[9];
    const float* Wl2 = (const float*)d_in[10];
    const float* bl2 = (const float*)d_in[11];
    const float* Wr2 = (const float*)d_in[12];
    const float* br2 = (const float*)d_in[13];
    const float* att2 = (const float*)d_in[14];
    const float* b2 = (const float*)d_in[15];

    const int* srcs = ei;
    const int* tgts = ei + EE;

    char* ws = (char*)d_ws;
    float* XLR1 = (float*)(ws + OFF_XLR1);
    unsigned short* H1B = (unsigned short*)(ws + OFF_H1B);
    float* XLR2 = (float*)(ws + OFF_XLR2);
    unsigned short* XBF = (unsigned short*)(ws + OFF_XBF);
    unsigned short* BP1 = (unsigned short*)(ws + OFF_BP1);
    unsigned short* BP2 = (unsigned short*)(ws + OFF_BP2);
    float* BB1 = (float*)(ws + OFF_BB1);
    float* BB2 = (float*)(ws + OFF_BB2);
    int* DEG = (int*)(ws + OFF_DEG);
    int* OFFS = (int*)(ws + OFF_OFFS);
    int* CUR = (int*)(ws + OFF_CUR);
    int* CSR = (int*)(ws + OFF_CSR);

    float* Y = (float*)d_out;

    // weights -> bf16 MFMA-fragment layout
    pack_weights_kernel<<<128, 256, 0, stream>>>(
        Wl1, bl1, Wr1, br1, Wl2, bl2, Wr2, br2, BP1, BB1, BP2, BB2);

    // x -> bf16 (N*128/8 = 800000 vector stores)
    cvt_bf16_kernel<<<(NN * 128 / 8 + 255) / 256, 256, 0, stream>>>(x, XBF, NN * 128 / 8);

    // CSR build
    zero_int_kernel<<<(NN + 255) / 256, 256, 0, stream>>>(DEG, NN);
    hist_kernel<<<(EE + 255) / 256, 256, 0, stream>>>(tgts, DEG, EE);
    scan_kernel<<<1, 1024, 0, stream>>>(DEG, OFFS, CUR, NN);
    scatter_kernel<<<(EE + 255) / 256, 256, 0, stream>>>(srcs, tgts, CUR, CSR, EE);

    // layer-1 GEMM (MFMA): XLR1 = x_bf16 @ WB1 + BB1   (waves = 50000/16 = 3125)
    gemm_mfma_kernel<<<(3125 + 3) / 4, 256, 0, stream>>>(XBF, BP1, BB1, XLR1, NN, 16);

    // layer-1 fused edge pass (+bias+LN+ELU) -> H1 (bf16)
    gat_edge1_kernel<<<(NN + 3) / 4, 256, 0, stream>>>(XLR1, OFFS, CSR, att1, b1, g1, be1, H1B);

    // layer-2 GEMM (MFMA): XLR2 = H1_bf16 @ WB2 + BB2
    gemm_mfma_kernel<<<(3125 + 3) / 4, 256, 0, stream>>>(H1B, BP2, BB2, XLR2, NN, 5);

    // layer-2 fused edge pass -> output
    gat_edge2_kernel<<<(NN + 3) / 4, 256, 0, stream>>>(XLR2, OFFS, CSR, att2, b2, Y);
}

// Round 5
// 222.171 us; speedup vs baseline: 1.5296x; 1.2803x over previous
//
#include <hip/hip_runtime.h>
#include <hip/hip_bf16.h>
#include <math.h>

// Problem constants
#define NN 50000
#define EE 800000
#define NEG_BIG (-3.0e38f)
#define RESCALE_THR 8.0f
#define NB_SCAN 49  // ceil(50000/1024)

typedef __attribute__((ext_vector_type(8))) short bf16x8;
typedef __attribute__((ext_vector_type(4))) float f32x4;
typedef __attribute__((ext_vector_type(8))) unsigned short ushortx8;

// ---------------- workspace layout (bytes), all 256B-aligned ----------------
#define OFF_XBF  ((size_t)0)                        // N*128 bf16 (x converted)
#define SZ_XBF   ((size_t)NN * 128 * 2)
#define OFF_XL1B (OFF_XBF + SZ_XBF)                 // N*128 bf16 (xl layer1)
#define SZ_XL1B  ((size_t)NN * 128 * 2)
#define OFF_XR1  (OFF_XL1B + SZ_XL1B)               // N*128 f32 (xr layer1)
#define SZ_XR1   ((size_t)NN * 128 * 4)
#define OFF_H1B  (OFF_XR1 + SZ_XR1)                 // N*128 bf16
#define SZ_H1B   ((size_t)NN * 128 * 2)
#define OFF_XL2B (OFF_H1B + SZ_H1B)                 // N*40 bf16
#define SZ_XL2B  ((size_t)NN * 40 * 2)
#define OFF_XR2  (OFF_XL2B + SZ_XL2B)               // N*40 f32
#define SZ_XR2   ((size_t)NN * 40 * 4)
#define OFF_BP1  (OFF_XR2 + SZ_XR2)                 // 4*16*64*8 bf16
#define SZ_BP1   ((size_t)32768 * 2)
#define OFF_BP2  (OFF_BP1 + SZ_BP1)                 // 4*5*64*8 bf16
#define SZ_BP2   ((size_t)10240 * 2)
#define OFF_BB1  (OFF_BP2 + SZ_BP2)                 // 256 f32
#define SZ_BB1   ((size_t)1024)
#define OFF_BB2  (OFF_BB1 + SZ_BB1)                 // 80 f32 (pad)
#define SZ_BB2   ((size_t)512)
#define OFF_DEG  (OFF_BB2 + SZ_BB2)                 // N int
#define SZ_DEG   ((size_t)NN * 4)
#define OFF_OFFS (OFF_DEG + SZ_DEG)                 // (N+1) int (pad)
#define SZ_OFFS  ((size_t)200192)
#define OFF_CUR  (OFF_OFFS + SZ_OFFS)               // N int
#define SZ_CUR   ((size_t)NN * 4)
#define OFF_CSR  (OFF_CUR + SZ_CUR)                 // E int
#define SZ_CSR   ((size_t)EE * 4)
#define OFF_BSUM (OFF_CSR + SZ_CSR)                 // 64 int
#define SZ_BSUM  ((size_t)256)

__device__ __forceinline__ unsigned short f2bf(float f) {
    union { float f; unsigned u; } v;
    v.f = f;
    unsigned r = v.u + 0x7fffu + ((v.u >> 16) & 1u);
    return (unsigned short)(r >> 16);
}
__device__ __forceinline__ float bfl(unsigned u) {
    union { unsigned u; float f; } v;
    v.u = u << 16;
    return v.f;
}
__device__ __forceinline__ float bfh(unsigned u) {
    union { unsigned u; float f; } v;
    v.u = u & 0xffff0000u;
    return v.f;
}

// ---------------- fused prep: zero DEG + pack weights + cvt x -> bf16 --------
__global__ void prep_kernel(
    const float* __restrict__ x, unsigned short* __restrict__ XBF,
    const float* __restrict__ Wl1, const float* __restrict__ bl1,
    const float* __restrict__ Wr1, const float* __restrict__ br1,
    const float* __restrict__ Wl2, const float* __restrict__ bl2,
    const float* __restrict__ Wr2, const float* __restrict__ br2,
    unsigned short* __restrict__ BP1, float* __restrict__ BB1,
    unsigned short* __restrict__ BP2, float* __restrict__ BB2,
    int* __restrict__ DEG) {
    int i = blockIdx.x * blockDim.x + threadIdx.x;
    if (i < NN * 128 / 8) {
        const float4* p = (const float4*)x + (size_t)i * 2;
        float4 v0 = p[0], v1 = p[1];
        ushortx8 o;
        o[0] = f2bf(v0.x); o[1] = f2bf(v0.y); o[2] = f2bf(v0.z); o[3] = f2bf(v0.w);
        o[4] = f2bf(v1.x); o[5] = f2bf(v1.y); o[6] = f2bf(v1.z); o[7] = f2bf(v1.w);
        *((ushortx8*)XBF + i) = o;
    }
    if (i < NN) DEG[i] = 0;
    if (i < 32768) {  // layer 1 B-pack: NT=16
        int j = i & 7, l = (i >> 3) & 63, nt = (i >> 9) & 15, kt = i >> 13;
        int k = kt * 32 + ((l >> 4) << 3) + j;
        int n = nt * 16 + (l & 15);
        float v = (n < 128) ? Wl1[k * 128 + n] : Wr1[k * 128 + (n - 128)];
        BP1[i] = f2bf(v);
    }
    if (i < 10240) {  // layer 2 B-pack: NT=5
        int j = i & 7, l = (i >> 3) & 63;
        int rest = i >> 9;
        int nt = rest % 5, kt = rest / 5;
        int k = kt * 32 + ((l >> 4) << 3) + j;
        int n = nt * 16 + (l & 15);
        float v = (n < 40) ? Wl2[k * 40 + n] : Wr2[k * 40 + (n - 40)];
        BP2[i] = f2bf(v);
    }
    if (i < 256) BB1[i] = (i < 128) ? bl1[i] : br1[i - 128];
    if (i < 80) BB2[i] = (i < 40) ? bl2[i] : br2[i - 40];
}

__global__ void hist_kernel(const int* __restrict__ tgts, int* __restrict__ deg, int e_) {
    int e = blockIdx.x * blockDim.x + threadIdx.x;
    if (e < e_) atomicAdd(&deg[tgts[e]], 1);
}

// ---------------- parallel 3-phase scan ----------------
__global__ __launch_bounds__(1024) void scan_bsum_kernel(
    const int* __restrict__ deg, int* __restrict__ bsum, int n) {
    __shared__ int ws[16];
    int lane = threadIdx.x & 63, w = threadIdx.x >> 6;
    int i = blockIdx.x * 1024 + threadIdx.x;
    int v = (i < n) ? deg[i] : 0;
#pragma unroll
    for (int d = 32; d >= 1; d >>= 1) v += __shfl_xor(v, d, 64);
    if (lane == 0) ws[w] = v;
    __syncthreads();
    if (threadIdx.x < 16) {
        int xv = ws[threadIdx.x];
#pragma unroll
        for (int d = 8; d >= 1; d >>= 1) xv += __shfl_xor(xv, d, 16);
        if (threadIdx.x == 0) bsum[blockIdx.x] = xv;
    }
}

__global__ void scan_boff_kernel(int* __restrict__ bsum, int nb) {
    int tid = threadIdx.x;  // 64 threads, one wave
    int v = (tid < nb) ? bsum[tid] : 0;
    int incl = v;
#pragma unroll
    for (int d = 1; d < 64; d <<= 1) {
        int t = __shfl_up(incl, d, 64);
        if (tid >= d) incl += t;
    }
    if (tid < nb) bsum[tid] = incl - v;  // exclusive block offsets
}

__global__ __launch_bounds__(1024) void scan_final_kernel(
    const int* __restrict__ deg, const int* __restrict__ bsum,
    int* __restrict__ off, int* __restrict__ cur, int n) {
    __shared__ int wsum[16];
    int lane = threadIdx.x & 63, w = threadIdx.x >> 6;
    int carry = bsum[blockIdx.x];
    int i = blockIdx.x * 1024 + threadIdx.x;
    int v = (i < n) ? deg[i] : 0;
    int incl = v;
#pragma unroll
    for (int d = 1; d < 64; d <<= 1) {
        int t = __shfl_up(incl, d, 64);
        if (lane >= d) incl += t;
    }
    if (lane == 63) wsum[w] = incl;
    __syncthreads();
    if (threadIdx.x < 16) {
        int xv = wsum[threadIdx.x];
#pragma unroll
        for (int d = 1; d < 16; d <<= 1) {
            int t = __shfl_up(xv, d, 16);
            if ((int)threadIdx.x >= d) xv += t;
        }
        wsum[threadIdx.x] = xv;
    }
    __syncthreads();
    int add = (w > 0) ? wsum[w - 1] : 0;
    if (i < n) {
        int tot = carry + incl + add;
        off[i + 1] = tot;
        cur[i] = tot - v;
    }
    if (i == 0) off[0] = 0;
}

__global__ void scatter_kernel(const int* __restrict__ srcs, const int* __restrict__ tgts,
                               int* __restrict__ cur, int* __restrict__ csr, int e_) {
    int e = blockIdx.x * blockDim.x + threadIdx.x;
    if (e < e_) {
        int t = tgts[e];
        int pos = atomicAdd(&cur[t], 1);
        csr[pos] = srcs[e];
    }
}

// ---------------- bf16 MFMA GEMM with split bf16/f32 output ------------------
// One wave per 16 rows (M = 50000 = 3125*16). K=128.
// cols c < NSPLIT -> Cbf[row*NSPLIT + c] (bf16); c >= NSPLIT -> Cf[row*(N-NSPLIT)+c-NSPLIT] (f32)
__global__ __launch_bounds__(256) void gemm_mfma_kernel(
    const unsigned short* __restrict__ Abf, const unsigned short* __restrict__ BP,
    const float* __restrict__ bias, unsigned short* __restrict__ Cbf,
    float* __restrict__ Cf, int M, int NT, int NSPLIT) {
    int wave = (blockIdx.x * blockDim.x + threadIdx.x) >> 6;
    int lane = threadIdx.x & 63;
    int r0 = wave * 16;
    if (r0 >= M) return;
    int koff = (lane >> 4) << 3;
    const unsigned short* ap = &Abf[(size_t)(r0 + (lane & 15)) * 128 + koff];
    bf16x8 a0 = *(const bf16x8*)(ap);
    bf16x8 a1 = *(const bf16x8*)(ap + 32);
    bf16x8 a2 = *(const bf16x8*)(ap + 64);
    bf16x8 a3 = *(const bf16x8*)(ap + 96);
    int NR = (NT << 4) - NSPLIT;
    int col = lane & 15;
    int rb = r0 + ((lane >> 4) << 2);
    size_t ktStride = (size_t)NT * 512;
    for (int nt = 0; nt < NT; ++nt) {
        const unsigned short* bp = &BP[((size_t)nt * 64 + lane) * 8];
        f32x4 acc = {0.f, 0.f, 0.f, 0.f};
        acc = __builtin_amdgcn_mfma_f32_16x16x32_bf16(a0, *(const bf16x8*)(bp), acc, 0, 0, 0);
        acc = __builtin_amdgcn_mfma_f32_16x16x32_bf16(a1, *(const bf16x8*)(bp + ktStride), acc, 0, 0, 0);
        acc = __builtin_amdgcn_mfma_f32_16x16x32_bf16(a2, *(const bf16x8*)(bp + 2 * ktStride), acc, 0, 0, 0);
        acc = __builtin_amdgcn_mfma_f32_16x16x32_bf16(a3, *(const bf16x8*)(bp + 3 * ktStride), acc, 0, 0, 0);
        int c = (nt << 4) + col;
        float bb = bias[c];
        if (c < NSPLIT) {
#pragma unroll
            for (int j = 0; j < 4; ++j) Cbf[(size_t)(rb + j) * NSPLIT + c] = f2bf(acc[j] + bb);
        } else {
#pragma unroll
            for (int j = 0; j < 4; ++j) Cf[(size_t)(rb + j) * NR + (c - NSPLIT)] = acc[j] + bb;
        }
    }
}

__device__ __forceinline__ float lrelu02(float h) { return fmaxf(h, 0.2f * h); }

// ---------------- layer-1 fused edge kernel (4 edges x 16 lanes per wave) ----
// xl gathered as bf16 (halves gather traffic); xr per-node f32.
__global__ __launch_bounds__(256) void gat_edge1_kernel(
    const unsigned short* __restrict__ XL1B, const float* __restrict__ XR1,
    const int* __restrict__ off, const int* __restrict__ csr,
    const float* __restrict__ att, const float* __restrict__ b1,
    const float* __restrict__ g1, const float* __restrict__ be1,
    unsigned short* __restrict__ H1B) {
    int wid = threadIdx.x >> 6;
    int lane = threadIdx.x & 63;
    int node = blockIdx.x * 4 + wid;
    if (node >= NN) return;
    int grp = lane >> 4;
    int sub = lane & 15;
    int cbase = sub << 3;
    const float* xrrow = &XR1[(size_t)node * 128];
    float4 xrA = *(const float4*)&xrrow[cbase];
    float4 xrB = *(const float4*)&xrrow[cbase + 4];
    float4 atA = *(const float4*)&att[cbase];
    float4 atB = *(const float4*)&att[cbase + 4];
    float m = NEG_BIG, s = 0.f;
    float acc[8] = {};
    int jb = off[node], je = off[node + 1];
    int nb = (je - jb + 3) >> 2;
#pragma unroll 2
    for (int k = 0; k < nb; ++k) {
        int eidx = jb + (k << 2) + grp;
        bool valid = eidx < je;
        int src = valid ? csr[eidx] : 0;
        uint4 q = *(const uint4*)&XL1B[(size_t)src * 128 + cbase];
        float x0 = bfl(q.x), x1 = bfh(q.x), x2 = bfl(q.y), x3 = bfh(q.y);
        float x4 = bfl(q.z), x5 = bfh(q.z), x6 = bfl(q.w), x7 = bfh(q.w);
        float t = lrelu02(x0 + xrA.x) * atA.x;
        t = fmaf(lrelu02(x1 + xrA.y), atA.y, t);
        t = fmaf(lrelu02(x2 + xrA.z), atA.z, t);
        t = fmaf(lrelu02(x3 + xrA.w), atA.w, t);
        t = fmaf(lrelu02(x4 + xrB.x), atB.x, t);
        t = fmaf(lrelu02(x5 + xrB.y), atB.y, t);
        t = fmaf(lrelu02(x6 + xrB.z), atB.z, t);
        t = fmaf(lrelu02(x7 + xrB.w), atB.w, t);
        t += __shfl_xor(t, 1, 64);
        t += __shfl_xor(t, 2, 64);
        bool need = valid && (t - m > RESCALE_THR);
        if (__any(need)) {  // rare: ~once per node
            float nm = need ? t : m;
            float sc = __expf(m - nm);
#pragma unroll
            for (int j = 0; j < 8; ++j) acc[j] *= sc;
            s *= sc;
            m = nm;
        }
        float p = valid ? __expf(t - m) : 0.f;
        acc[0] = fmaf(p, x0, acc[0]);
        acc[1] = fmaf(p, x1, acc[1]);
        acc[2] = fmaf(p, x2, acc[2]);
        acc[3] = fmaf(p, x3, acc[3]);
        acc[4] = fmaf(p, x4, acc[4]);
        acc[5] = fmaf(p, x5, acc[5]);
        acc[6] = fmaf(p, x6, acc[6]);
        acc[7] = fmaf(p, x7, acc[7]);
        s += p;
    }
    // merge the 4 groups' states
#pragma unroll
    for (int d = 16; d <= 32; d <<= 1) {
        float mo = __shfl_xor(m, d, 64);
        float so = __shfl_xor(s, d, 64);
        float ao[8];
#pragma unroll
        for (int j = 0; j < 8; ++j) ao[j] = __shfl_xor(acc[j], d, 64);
        float nm = fmaxf(m, mo);
        float sa = __expf(m - nm), sb = __expf(mo - nm);
#pragma unroll
        for (int j = 0; j < 8; ++j) acc[j] = acc[j] * sa + ao[j] * sb;
        s = s * sa + so * sb;
        m = nm;
    }
    float inv = 1.f / (s + 1e-16f);
    float4 bA = *(const float4*)&b1[cbase];
    float4 bB = *(const float4*)&b1[cbase + 4];
    float o[8];
    o[0] = acc[0] * inv + bA.x;
    o[1] = acc[1] * inv + bA.y;
    o[2] = acc[2] * inv + bA.z;
    o[3] = acc[3] * inv + bA.w;
    o[4] = acc[4] * inv + bB.x;
    o[5] = acc[5] * inv + bB.y;
    o[6] = acc[6] * inv + bB.z;
    o[7] = acc[7] * inv + bB.w;
    float sum = 0.f, sq = 0.f;
#pragma unroll
    for (int j = 0; j < 8; ++j) {
        sum += o[j];
        sq = fmaf(o[j], o[j], sq);
    }
#pragma unroll
    for (int d = 1; d <= 8; d <<= 1) {
        sum += __shfl_xor(sum, d, 64);
        sq += __shfl_xor(sq, d, 64);
    }
    float mu = sum * (1.f / 128.f);
    float var = sq * (1.f / 128.f) - mu * mu;
    float rs = rsqrtf(var + 1e-5f);
    if (grp == 0) {
        float4 gA = *(const float4*)&g1[cbase];
        float4 gB = *(const float4*)&g1[cbase + 4];
        float4 eA = *(const float4*)&be1[cbase];
        float4 eB = *(const float4*)&be1[cbase + 4];
        float y[8];
        y[0] = (o[0] - mu) * rs * gA.x + eA.x;
        y[1] = (o[1] - mu) * rs * gA.y + eA.y;
        y[2] = (o[2] - mu) * rs * gA.z + eA.z;
        y[3] = (o[3] - mu) * rs * gA.w + eA.w;
        y[4] = (o[4] - mu) * rs * gB.x + eB.x;
        y[5] = (o[5] - mu) * rs * gB.y + eB.y;
        y[6] = (o[6] - mu) * rs * gB.z + eB.z;
        y[7] = (o[7] - mu) * rs * gB.w + eB.w;
        ushortx8 hw;
#pragma unroll
        for (int j = 0; j < 8; ++j) {
            float yy = y[j] > 0.f ? y[j] : expm1f(y[j]);
            hw[j] = f2bf(yy);
        }
        *(ushortx8*)&H1B[(size_t)node * 128 + cbase] = hw;
    }
}

// ---------------- layer-2 fused edge kernel (4 edges x 16 lanes) -------------
__global__ __launch_bounds__(256) void gat_edge2_kernel(
    const unsigned short* __restrict__ XL2B, const float* __restrict__ XR2,
    const int* __restrict__ off, const int* __restrict__ csr,
    const float* __restrict__ att2, const float* __restrict__ b2,
    float* __restrict__ Y) {
    int wid = threadIdx.x >> 6;
    int lane = threadIdx.x & 63;
    int node = blockIdx.x * 4 + wid;
    if (node >= NN) return;
    int grp = lane >> 4;
    int sub = lane & 15;
    bool chact = sub < 10;
    int cbase = sub << 2;
    float4 xr = make_float4(0.f, 0.f, 0.f, 0.f);
    float4 at = make_float4(0.f, 0.f, 0.f, 0.f);
    if (chact) {
        xr = *(const float4*)&XR2[(size_t)node * 40 + cbase];
        at = *(const float4*)&att2[cbase];
    }
    float m = NEG_BIG, s = 0.f;
    float acc[4] = {};
    int jb = off[node], je = off[node + 1];
    int nb = (je - jb + 3) >> 2;
#pragma unroll 2
    for (int k = 0; k < nb; ++k) {
        int eidx = jb + (k << 2) + grp;
        bool valid = eidx < je;
        int src = valid ? csr[eidx] : 0;
        float x0 = 0.f, x1 = 0.f, x2 = 0.f, x3 = 0.f;
        if (chact) {
            uint2 q = *(const uint2*)&XL2B[(size_t)src * 40 + cbase];
            x0 = bfl(q.x); x1 = bfh(q.x); x2 = bfl(q.y); x3 = bfh(q.y);
        }
        float t = lrelu02(x0 + xr.x) * at.x;
        t = fmaf(lrelu02(x1 + xr.y), at.y, t);
        t = fmaf(lrelu02(x2 + xr.z), at.z, t);
        t = fmaf(lrelu02(x3 + xr.w), at.w, t);
        t += __shfl_xor(t, 1, 64);
        t += __shfl_xor(t, 2, 64);
        t += __shfl_xor(t, 4, 64);
        t += __shfl_xor(t, 8, 64);
        bool need = valid && (t - m > RESCALE_THR);
        if (__any(need)) {
            float nm = need ? t : m;
            float sc = __expf(m - nm);
            acc[0] *= sc;
            acc[1] *= sc;
            acc[2] *= sc;
            acc[3] *= sc;
            s *= sc;
            m = nm;
        }
        float p = valid ? __expf(t - m) : 0.f;
        acc[0] = fmaf(p, x0, acc[0]);
        acc[1] = fmaf(p, x1, acc[1]);
        acc[2] = fmaf(p, x2, acc[2]);
        acc[3] = fmaf(p, x3, acc[3]);
        s += p;
    }
#pragma unroll
    for (int d = 16; d <= 32; d <<= 1) {
        float mo = __shfl_xor(m, d, 64);
        float so = __shfl_xor(s, d, 64);
        float a0 = __shfl_xor(acc[0], d, 64);
        float a1 = __shfl_xor(acc[1], d, 64);
        float a2 = __shfl_xor(acc[2], d, 64);
        float a3 = __shfl_xor(acc[3], d, 64);
        float nm = fmaxf(m, mo);
        float sa = __expf(m - nm), sb = __expf(mo - nm);
        acc[0] = acc[0] * sa + a0 * sb;
        acc[1] = acc[1] * sa + a1 * sb;
        acc[2] = acc[2] * sa + a2 * sb;
        acc[3] = acc[3] * sa + a3 * sb;
        s = s * sa + so * sb;
        m = nm;
    }
    if (grp == 0 && chact) {
        float inv = 1.f / (s + 1e-16f);
        float4 bb = *(const float4*)&b2[cbase];
        float4 y;
        y.x = acc[0] * inv + bb.x;
        y.y = acc[1] * inv + bb.y;
        y.z = acc[2] * inv + bb.z;
        y.w = acc[3] * inv + bb.w;
        *(float4*)&Y[(size_t)node * 40 + cbase] = y;
    }
}

// ---------------- launch ----------------
extern "C" void kernel_launch(void* const* d_in, const int* in_sizes, int n_in,
                              void* d_out, int out_size, void* d_ws, size_t ws_size,
                              hipStream_t stream) {
    const float* x = (const float*)d_in[0];
    const int* ei = (const int*)d_in[1];
    const float* Wl1 = (const float*)d_in[2];
    const float* bl1 = (const float*)d_in[3];
    const float* Wr1 = (const float*)d_in[4];
    const float* br1 = (const float*)d_in[5];
    const float* att1 = (const float*)d_in[6];
    const float* b1 = (const float*)d_in[7];
    const float* g1 = (const float*)d_in[8];
    const float* be1 = (const float*)d_in[9];
    const float* Wl2 = (const float*)d_in[10];
    const float* bl2 = (const float*)d_in[11];
    const float* Wr2 = (const float*)d_in[12];
    const float* br2 = (const float*)d_in[13];
    const float* att2 = (const float*)d_in[14];
    const float* b2 = (const float*)d_in[15];

    const int* srcs = ei;
    const int* tgts = ei + EE;

    char* ws = (char*)d_ws;
    unsigned short* XBF = (unsigned short*)(ws + OFF_XBF);
    unsigned short* XL1B = (unsigned short*)(ws + OFF_XL1B);
    float* XR1 = (float*)(ws + OFF_XR1);
    unsigned short* H1B = (unsigned short*)(ws + OFF_H1B);
    unsigned short* XL2B = (unsigned short*)(ws + OFF_XL2B);
    float* XR2 = (float*)(ws + OFF_XR2);
    unsigned short* BP1 = (unsigned short*)(ws + OFF_BP1);
    unsigned short* BP2 = (unsigned short*)(ws + OFF_BP2);
    float* BB1 = (float*)(ws + OFF_BB1);
    float* BB2 = (float*)(ws + OFF_BB2);
    int* DEG = (int*)(ws + OFF_DEG);
    int* OFFS = (int*)(ws + OFF_OFFS);
    int* CUR = (int*)(ws + OFF_CUR);
    int* CSR = (int*)(ws + OFF_CSR);
    int* BSUM = (int*)(ws + OFF_BSUM);

    float* Y = (float*)d_out;

    // prep: zero DEG + pack weights + x->bf16
    prep_kernel<<<(NN * 128 / 8 + 255) / 256, 256, 0, stream>>>(
        x, XBF, Wl1, bl1, Wr1, br1, Wl2, bl2, Wr2, br2, BP1, BB1, BP2, BB2, DEG);

    // CSR build (parallel scan)
    hist_kernel<<<(EE + 255) / 256, 256, 0, stream>>>(tgts, DEG, EE);
    scan_bsum_kernel<<<NB_SCAN, 1024, 0, stream>>>(DEG, BSUM, NN);
    scan_boff_kernel<<<1, 64, 0, stream>>>(BSUM, NB_SCAN);
    scan_final_kernel<<<NB_SCAN, 1024, 0, stream>>>(DEG, BSUM, OFFS, CUR, NN);
    scatter_kernel<<<(EE + 255) / 256, 256, 0, stream>>>(srcs, tgts, CUR, CSR, EE);

    // layer-1 GEMM (MFMA): xl -> bf16 XL1B, xr -> f32 XR1
    gemm_mfma_kernel<<<(3125 + 3) / 4, 256, 0, stream>>>(XBF, BP1, BB1, XL1B, XR1, NN, 16, 128);

    // layer-1 fused edge pass (+bias+LN+ELU) -> H1 (bf16)
    gat_edge1_kernel<<<(NN + 3) / 4, 256, 0, stream>>>(XL1B, XR1, OFFS, CSR, att1, b1, g1, be1, H1B);

    // layer-2 GEMM (MFMA): xl -> bf16 XL2B, xr -> f32 XR2
    gemm_mfma_kernel<<<(3125 + 3) / 4, 256, 0, stream>>>(H1B, BP2, BB2, XL2B, XR2, NN, 5, 40);

    // layer-2 fused edge pass -> output
    gat_edge2_kernel<<<(NN + 3) / 4, 256, 0, stream>>>(XL2B, XR2, OFFS, CSR, att2, b2, Y);
}